// Round 6
// baseline (1157.859 us; speedup 1.0000x reference)
//
#include <hip/hip_runtime.h>
#include <hip/hip_bf16.h>

#define N_NODES   100000
#define N_EDGES   3200000
#define F_IN      100
#define H_DIM     64
#define C_NUM     18
#define NPB       1024                      // nodes per bucket
#define N_BKT     98                        // ceil(100000/1024)
#define N_SUB     32                        // sub-regions per bucket (writer partition)
#define N_PART    (N_BKT * N_SUB)           // 3136

typedef __attribute__((ext_vector_type(8))) short short8;
typedef __attribute__((ext_vector_type(4))) float f32x4;

// ---- dtype-flexible loads (flags decided at runtime by detect_kernel) ----
__device__ __forceinline__ float ldf(const void* p, long long i, int isbf) {
    if (isbf) return __bfloat162float(((const __hip_bfloat16*)p)[i]);
    return ((const float*)p)[i];
}
__device__ __forceinline__ int ldi(const void* p, long long i, int is64) {
    if (is64) return (int)(((const long long*)p)[i]);
    return ((const int*)p)[i];
}
__device__ __forceinline__ unsigned short f2us(float f) {
    __hip_bfloat16 b = __float2bfloat16(f);
    return *(unsigned short*)&b;
}

// ---- probe input dtypes; write flags ----
__global__ void detect_kernel(const void* ei, const void* x, int* flags)
{
    if (threadIdx.x != 0 || blockIdx.x != 0) return;
    const long long* e64 = (const long long*)ei;
    int ok64 = 1;
    for (int i = 0; i < 128; ++i) {
        long long v = e64[i];
        if (v < 0 || v >= N_NODES) { ok64 = 0; break; }
    }
    const __hip_bfloat16* xb = (const __hip_bfloat16*)x;
    int cnt = 0;
    for (int i = 0; i < 256; ++i) {
        float v = fabsf(__bfloat162float(xb[i]));
        if (v == 0.0f || (v > 9.5367431640625e-7f && v < 1.0e6f)) ++cnt;
    }
    flags[0] = ok64;
    flags[1] = (cnt >= 240) ? 1 : 0;
}

__global__ void zero_parts(int* __restrict__ pcnt)
{
    int i = blockIdx.x * blockDim.x + threadIdx.x;
    if (i < N_PART) pcnt[i] = 0;
}

// ---- pass A: per-(bucket,sub) sizes; sub = blockIdx%32 (same mapping as scatter) ----
__global__ void bucket_count(const void* ei, int* __restrict__ pcnt,
                             const int* __restrict__ flags)
{
    int e = blockIdx.x * blockDim.x + threadIdx.x;
    if (e >= N_EDGES) return;
    int d = ldi(ei, (long long)N_EDGES + e, flags[0]);
    atomicAdd(&pcnt[((d >> 10) << 5) | (blockIdx.x & (N_SUB - 1))], 1);
}

// ---- prefix scan over N_PART partition counts (single block) ----
__global__ void scan_kernel(const int* __restrict__ cnt, int* __restrict__ base,
                            int* __restrict__ cursor)
{
    __shared__ int tmp[1024];
    __shared__ int carry_s;
    const int t = threadIdx.x;
    if (t == 0) carry_s = 0;
    __syncthreads();
    for (int c0 = 0; c0 < N_PART; c0 += 1024) {
        int i = c0 + t;
        int v = (i < N_PART) ? cnt[i] : 0;
        tmp[t] = v;
        __syncthreads();
        for (int off = 1; off < 1024; off <<= 1) {
            int add = (t >= off) ? tmp[t - off] : 0;
            __syncthreads();
            tmp[t] += add;
            __syncthreads();
        }
        int carry = carry_s;
        int excl  = carry + tmp[t] - v;
        if (i < N_PART) { base[i] = excl; cursor[i] = excl; }
        int tot = tmp[1023];
        __syncthreads();
        if (t == 0) carry_s = carry + tot;
        __syncthreads();
    }
    if (t == 0) base[N_PART] = carry_s;   // == N_EDGES
}

// ---- pass B: scatter edges into contiguous (bucket,sub) regions ----
__global__ void bucket_scatter(const void* ei, const void* ew,
                               int* __restrict__ cursor, uint2* __restrict__ temp,
                               const int* __restrict__ flags)
{
    int e = blockIdx.x * blockDim.x + threadIdx.x;
    if (e >= N_EDGES) return;
    const int is64 = flags[0];
    int s = ldi(ei, e, is64);
    int d = ldi(ei, (long long)N_EDGES + e, is64);
    float w = ldf(ew, e, flags[1]);
    int part = ((d >> 10) << 5) | (blockIdx.x & (N_SUB - 1));
    int pos = atomicAdd(&cursor[part], 1);
    uint2 v;
    v.x = (unsigned)s | ((unsigned)(d & (NPB - 1)) << 17);   // src:17b | dst-low:10b
    v.y = (unsigned)f2us(w);
    temp[pos] = v;
}

// ---- pass C: per-bucket CSR finalize (1024 nodes); writes deg/row_start/inv_deg ----
// csr entry: src:17b | bf16-weight-without-sign:15b (weights >= 0)
__global__ void csr_build(const uint2* __restrict__ temp,
                          const int* __restrict__ pbase,
                          unsigned int* __restrict__ csr_pk,
                          int* __restrict__ deg, int* __restrict__ row_start,
                          float* __restrict__ inv_deg)
{
    __shared__ int cnt[NPB], scan_s[NPB], cur[NPB];
    const int b = blockIdx.x;
    const int t = threadIdx.x;
    cnt[t] = 0;
    __syncthreads();
    const int bs = pbase[b * N_SUB];
    const int be = pbase[(b + 1) * N_SUB];
    for (int i = bs + t; i < be; i += NPB)
        atomicAdd(&cnt[(temp[i].x >> 17) & (NPB - 1)], 1);
    __syncthreads();
    int v = cnt[t];
    scan_s[t] = v;
    __syncthreads();
    for (int off = 1; off < NPB; off <<= 1) {
        int add = (t >= off) ? scan_s[t - off] : 0;
        __syncthreads();
        scan_s[t] += add;
        __syncthreads();
    }
    int excl = bs + scan_s[t] - v;
    cur[t] = excl;
    int node = b * NPB + t;
    if (node < N_NODES) {
        deg[node]       = v;
        row_start[node] = excl;
        inv_deg[node]   = 1.0f / (float)max(v, 1);
    }
    __syncthreads();
    for (int i = bs + t; i < be; i += NPB) {
        uint2 e = temp[i];
        int k = (e.x >> 17) & (NPB - 1);
        int pos = atomicAdd(&cur[k], 1);
        csr_pk[pos] = (e.x & 0x1FFFFu) | ((e.y & 0x7FFFu) << 17);
    }
}

// ---- embedding via MFMA: h = relu(x @ W + b), [N,100pad128] @ [128,64] ----
__global__ void embed_mfma(const void* x, const void* W, const void* b,
                           __hip_bfloat16* __restrict__ h, const int* __restrict__ flags)
{
    constexpr int KP = 136;
    __shared__ unsigned short W_s[H_DIM * KP];
    __shared__ float b_s[H_DIM];
    const int t = threadIdx.x;
    const int isbf = flags[1];
    for (int i = t; i < 128 * H_DIM; i += 256) {
        int k = i >> 6, n = i & 63;
        float v = (k < F_IN) ? ldf(W, (long long)k * H_DIM + n, isbf) : 0.0f;
        W_s[n * KP + k] = f2us(v);
    }
    if (t < H_DIM) b_s[t] = ldf(b, t, isbf);
    __syncthreads();

    const int wave = t >> 6, lane = t & 63, c = lane & 15, quad = lane >> 4;
    short8 bfrag[4][4];
#pragma unroll
    for (int nt = 0; nt < 4; ++nt)
#pragma unroll
        for (int kt = 0; kt < 4; ++kt)
            bfrag[nt][kt] = *(const short8*)&W_s[(nt * 16 + c) * KP + kt * 32 + quad * 8];

    const int nb = (blockIdx.x * 4 + wave) * 16;
    if (nb >= N_NODES) return;
    int node = nb + c; if (node >= N_NODES) node = N_NODES - 1;

    short8 afrag[4];
#pragma unroll
    for (int kt = 0; kt < 4; ++kt) {
        short8 a;
#pragma unroll
        for (int j = 0; j < 8; ++j) {
            int k = kt * 32 + quad * 8 + j;
            float v = (k < F_IN) ? ldf(x, (long long)node * F_IN + k, isbf) : 0.0f;
            a[j] = (short)f2us(v);
        }
        afrag[kt] = a;
    }

    f32x4 acc[4] = {};
#pragma unroll
    for (int nt = 0; nt < 4; ++nt)
#pragma unroll
        for (int kt = 0; kt < 4; ++kt)
            acc[nt] = __builtin_amdgcn_mfma_f32_16x16x32_bf16(afrag[kt], bfrag[nt][kt], acc[nt], 0, 0, 0);

#pragma unroll
    for (int nt = 0; nt < 4; ++nt)
#pragma unroll
        for (int reg = 0; reg < 4; ++reg) {
            int nn = nb + quad * 4 + reg;
            int col = nt * 16 + c;
            if (nn < N_NODES) {
                float v = fmaxf(acc[nt][reg] + b_s[col], 0.0f);
                h[(size_t)nn * H_DIM + col] = __float2bfloat16(v);
            }
        }
}

// ---- gather: mean[n] = inv_deg * sum_j w_j * h[src_j], wave per node ----
// lane = (r,c): r = neighbor sub-index (8), c = feature oct (8 x 8 features, 16B loads)
template <bool USE_W>
__global__ void gather_mean(const __hip_bfloat16* __restrict__ h,
                            const unsigned int* __restrict__ csr_pk,
                            const int* __restrict__ row_start,
                            const int* __restrict__ deg,
                            const float* __restrict__ inv_deg,
                            __hip_bfloat16* __restrict__ mean)
{
    const int lane = threadIdx.x & 63;
    const int c = lane & 7;
    const int r = lane >> 3;
    const int wid = blockIdx.x * 4 + (threadIdx.x >> 6);
    const int nw  = gridDim.x * 4;

    for (int n = wid; n < N_NODES; n += nw) {
        const int start = row_start[n];
        const int d     = deg[n];
        // cooperative load: 64 lanes grab first 64 packed entries in one shot
        unsigned int ev = 0;
        if (lane < d) ev = csr_pk[start + lane];
        const int dmain = min(d, 64);
        float a0 = 0.f, a1 = 0.f, a2 = 0.f, a3 = 0.f;
        float a4 = 0.f, a5 = 0.f, a6 = 0.f, a7 = 0.f;
#pragma unroll 2
        for (int j0 = 0; j0 < dmain; j0 += 8) {
            unsigned int e = __shfl(ev, j0 + r);
            int s = e & 0x1FFFF;                 // invalid lanes: ev=0 -> s=0, w=0
            float w;
            if (USE_W) w = __uint_as_float((e & 0xFFFE0000u) >> 1);
            else       w = (j0 + r < dmain) ? 1.0f : 0.0f;
            uint4 hv = *(const uint4*)(h + (size_t)s * H_DIM + 8 * c);
            a0 = fmaf(w, __uint_as_float(hv.x << 16),          a0);
            a1 = fmaf(w, __uint_as_float(hv.x & 0xFFFF0000u),  a1);
            a2 = fmaf(w, __uint_as_float(hv.y << 16),          a2);
            a3 = fmaf(w, __uint_as_float(hv.y & 0xFFFF0000u),  a3);
            a4 = fmaf(w, __uint_as_float(hv.z << 16),          a4);
            a5 = fmaf(w, __uint_as_float(hv.z & 0xFFFF0000u),  a5);
            a6 = fmaf(w, __uint_as_float(hv.w << 16),          a6);
            a7 = fmaf(w, __uint_as_float(hv.w & 0xFFFF0000u),  a7);
        }
        // rare tail (deg > 64): direct loads
        for (int j = 64 + r; j < d; j += 8) {
            unsigned int e = csr_pk[start + j];
            int s = e & 0x1FFFF;
            float w = USE_W ? __uint_as_float((e & 0xFFFE0000u) >> 1) : 1.0f;
            uint4 hv = *(const uint4*)(h + (size_t)s * H_DIM + 8 * c);
            a0 = fmaf(w, __uint_as_float(hv.x << 16),          a0);
            a1 = fmaf(w, __uint_as_float(hv.x & 0xFFFF0000u),  a1);
            a2 = fmaf(w, __uint_as_float(hv.y << 16),          a2);
            a3 = fmaf(w, __uint_as_float(hv.y & 0xFFFF0000u),  a3);
            a4 = fmaf(w, __uint_as_float(hv.z << 16),          a4);
            a5 = fmaf(w, __uint_as_float(hv.z & 0xFFFF0000u),  a5);
            a6 = fmaf(w, __uint_as_float(hv.w << 16),          a6);
            a7 = fmaf(w, __uint_as_float(hv.w & 0xFFFF0000u),  a7);
        }
#pragma unroll
        for (int m = 8; m <= 32; m <<= 1) {
            a0 += __shfl_xor(a0, m); a1 += __shfl_xor(a1, m);
            a2 += __shfl_xor(a2, m); a3 += __shfl_xor(a3, m);
            a4 += __shfl_xor(a4, m); a5 += __shfl_xor(a5, m);
            a6 += __shfl_xor(a6, m); a7 += __shfl_xor(a7, m);
        }
        if (r == 0) {
            float inv = inv_deg[n];
            uint4 st;
            st.x = (unsigned)f2us(a0 * inv) | ((unsigned)f2us(a1 * inv) << 16);
            st.y = (unsigned)f2us(a2 * inv) | ((unsigned)f2us(a3 * inv) << 16);
            st.z = (unsigned)f2us(a4 * inv) | ((unsigned)f2us(a5 * inv) << 16);
            st.w = (unsigned)f2us(a6 * inv) | ((unsigned)f2us(a7 * inv) << 16);
            *(uint4*)(mean + (size_t)n * H_DIM + 8 * c) = st;
        }
    }
}

// ---- transform via MFMA: out = L2norm([mean|h] @ [Wl;Wr] + b), opt relu ----
template <int COUT, bool RELU, bool FINAL>
__global__ void transform_mfma(const __hip_bfloat16* __restrict__ meanp,
                               const __hip_bfloat16* __restrict__ hp,
                               const void* Wl, const void* bl, const void* Wr,
                               __hip_bfloat16* __restrict__ h_out,
                               const int* __restrict__ flags, void* dout)
{
    constexpr int CP = (COUT + 15) & ~15;
    constexpr int NT = CP / 16;
    constexpr int KP = 136;
    __shared__ unsigned short W_s[CP * KP];
    __shared__ float b_s[CP];
    const int t = threadIdx.x;
    const int isbf = flags[1];
    for (int i = t; i < 128 * CP; i += 256) {
        int k = i / CP, n = i % CP;
        float v = 0.0f;
        if (n < COUT)
            v = (k < 64) ? ldf(Wl, (long long)k * COUT + n, isbf)
                         : ldf(Wr, (long long)(k - 64) * COUT + n, isbf);
        W_s[n * KP + k] = f2us(v);
    }
    if (t < CP) b_s[t] = (t < COUT) ? ldf(bl, t, isbf) : 0.0f;
    __syncthreads();

    const int wave = t >> 6, lane = t & 63, c = lane & 15, quad = lane >> 4;
    short8 bfrag[NT][4];
#pragma unroll
    for (int nt = 0; nt < NT; ++nt)
#pragma unroll
        for (int kt = 0; kt < 4; ++kt)
            bfrag[nt][kt] = *(const short8*)&W_s[(nt * 16 + c) * KP + kt * 32 + quad * 8];

    const int nb = (blockIdx.x * 4 + wave) * 16;
    if (nb >= N_NODES) return;
    int node = nb + c; if (node >= N_NODES) node = N_NODES - 1;

    short8 afrag[4];
#pragma unroll
    for (int kt = 0; kt < 4; ++kt) {
        const __hip_bfloat16* sp = (kt < 2) ? meanp : hp;
        afrag[kt] = *(const short8*)(sp + (size_t)node * H_DIM + (kt & 1) * 32 + quad * 8);
    }

    f32x4 acc[NT] = {};
#pragma unroll
    for (int nt = 0; nt < NT; ++nt)
#pragma unroll
        for (int kt = 0; kt < 4; ++kt)
            acc[nt] = __builtin_amdgcn_mfma_f32_16x16x32_bf16(afrag[kt], bfrag[nt][kt], acc[nt], 0, 0, 0);

    float rs[4];
#pragma unroll
    for (int reg = 0; reg < 4; ++reg) {
        float s2 = 0.f;
#pragma unroll
        for (int nt = 0; nt < NT; ++nt) {
            float v = acc[nt][reg] + b_s[nt * 16 + c];
            acc[nt][reg] = v;
            s2 += v * v;
        }
        s2 += __shfl_xor(s2, 1); s2 += __shfl_xor(s2, 2);
        s2 += __shfl_xor(s2, 4); s2 += __shfl_xor(s2, 8);
        rs[reg] = 1.0f / fmaxf(sqrtf(s2), 1e-12f);
    }

#pragma unroll
    for (int nt = 0; nt < NT; ++nt)
#pragma unroll
        for (int reg = 0; reg < 4; ++reg) {
            int nn  = nb + quad * 4 + reg;
            int col = nt * 16 + c;
            if (nn < N_NODES && col < COUT) {
                float v = acc[nt][reg] * rs[reg];
                if (RELU) v = fmaxf(v, 0.0f);
                if (FINAL) {
                    if (isbf) ((__hip_bfloat16*)dout)[(size_t)nn * COUT + col] = __float2bfloat16(v);
                    else      ((float*)dout)[(size_t)nn * COUT + col] = v;
                } else {
                    h_out[(size_t)nn * H_DIM + col] = __float2bfloat16(v);
                }
            }
        }
}

extern "C" void kernel_launch(void* const* d_in, const int* in_sizes, int n_in,
                              void* d_out, int out_size, void* d_ws, size_t ws_size,
                              hipStream_t stream)
{
    const void* x    = d_in[0];
    const void* ei   = d_in[1];
    const void* ew   = d_in[2];
    const void* embW = d_in[3];
    const void* embB = d_in[4];
    const void* Wl1 = d_in[5];  const void* bl1 = d_in[6];  const void* Wr1 = d_in[7];
    const void* Wl2 = d_in[8];  const void* bl2 = d_in[9];  const void* Wr2 = d_in[10];
    const void* Wl3 = d_in[11]; const void* bl3 = d_in[12]; const void* Wr3 = d_in[13];
    const void* Wl4 = d_in[14]; const void* bl4 = d_in[15]; const void* Wr4 = d_in[16];
    (void)in_sizes; (void)n_in; (void)out_size; (void)ws_size;

    char* ws = (char*)d_ws;
    size_t off = 0;
    auto alloc = [&](size_t bytes) -> void* {
        void* p = ws + off;
        off += (bytes + 255) & ~(size_t)255;
        return p;
    };
    // temp (edge staging, 25.6 MB) is dead after csr_build; hA/hB alias it.
    uint2* temp = (uint2*)alloc((size_t)N_EDGES * sizeof(uint2));
    __hip_bfloat16* hA = (__hip_bfloat16*)temp;
    __hip_bfloat16* hB = (__hip_bfloat16*)((char*)temp + (size_t)N_NODES * H_DIM * 2);
    unsigned int* csr_pk = (unsigned int*)alloc((size_t)N_EDGES * sizeof(unsigned int));
    int*   pcnt    = (int*)  alloc((N_PART)     * sizeof(int));
    int*   pbase   = (int*)  alloc((N_PART + 1) * sizeof(int));
    int*   pcursor = (int*)  alloc((N_PART)     * sizeof(int));
    int*   deg     = (int*)  alloc((size_t)N_NODES * sizeof(int));
    int*   row_st  = (int*)  alloc((size_t)N_NODES * sizeof(int));
    float* inv_deg = (float*)alloc((size_t)N_NODES * sizeof(float));
    int*   flags   = (int*)  alloc(256);

    const int NBe = (N_EDGES + 255) / 256;     // 12500
    const int NBp = (N_PART + 255) / 256;      // 13
    const int NBt = (N_NODES + 63) / 64;       // 1563

    detect_kernel<<<1, 64, 0, stream>>>(ei, x, flags);
    zero_parts<<<NBp, 256, 0, stream>>>(pcnt);
    bucket_count<<<NBe, 256, 0, stream>>>(ei, pcnt, flags);
    scan_kernel<<<1, 1024, 0, stream>>>(pcnt, pbase, pcursor);
    bucket_scatter<<<NBe, 256, 0, stream>>>(ei, ew, pcursor, temp, flags);
    csr_build<<<N_BKT, NPB, 0, stream>>>(temp, pbase, csr_pk, deg, row_st, inv_deg);

    embed_mfma<<<NBt, 256, 0, stream>>>(x, embW, embB, hA, flags);

    // layer 1: h=A -> mean in B, out overwrites B
    gather_mean<true><<<2048, 256, 0, stream>>>(hA, csr_pk, row_st, deg, inv_deg, hB);
    transform_mfma<H_DIM, true, false><<<NBt, 256, 0, stream>>>(
        hB, hA, Wl1, bl1, Wr1, hB, flags, d_out);
    // layer 2: h=B -> mean in A, out overwrites A
    gather_mean<true><<<2048, 256, 0, stream>>>(hB, csr_pk, row_st, deg, inv_deg, hA);
    transform_mfma<H_DIM, true, false><<<NBt, 256, 0, stream>>>(
        hA, hB, Wl2, bl2, Wr2, hA, flags, d_out);
    // layer 3: h=A -> mean in B, out overwrites B
    gather_mean<true><<<2048, 256, 0, stream>>>(hA, csr_pk, row_st, deg, inv_deg, hB);
    transform_mfma<H_DIM, true, false><<<NBt, 256, 0, stream>>>(
        hB, hA, Wl3, bl3, Wr3, hB, flags, d_out);
    // layer 4: h=B -> mean in A (unweighted), out -> d_out
    gather_mean<false><<<2048, 256, 0, stream>>>(hB, csr_pk, row_st, deg, inv_deg, hA);
    transform_mfma<C_NUM, false, true><<<NBt, 256, 0, stream>>>(
        hA, hB, Wl4, bl4, Wr4, nullptr, flags, d_out);
}

// Round 7
// 551.402 us; speedup vs baseline: 2.0998x; 2.0998x over previous
//
#include <hip/hip_runtime.h>
#include <hip/hip_bf16.h>

#define N_NODES   100000
#define N_EDGES   3200000
#define F_IN      100
#define H_DIM     64
#define C_NUM     18
#define NPB       1024                      // nodes per bucket
#define N_BKT     98                        // ceil(100000/1024)
#define EPB       8192                      // edges per radix block

typedef __attribute__((ext_vector_type(8))) short short8;
typedef __attribute__((ext_vector_type(4))) float f32x4;

// ---- dtype-flexible loads (flags decided at runtime by detect_kernel) ----
__device__ __forceinline__ float ldf(const void* p, long long i, int isbf) {
    if (isbf) return __bfloat162float(((const __hip_bfloat16*)p)[i]);
    return ((const float*)p)[i];
}
__device__ __forceinline__ int ldi(const void* p, long long i, int is64) {
    if (is64) return (int)(((const long long*)p)[i]);
    return ((const int*)p)[i];
}
__device__ __forceinline__ unsigned short f2us(float f) {
    __hip_bfloat16 b = __float2bfloat16(f);
    return *(unsigned short*)&b;
}

// ---- probe input dtypes; write flags ----
__global__ void detect_kernel(const void* ei, const void* x, int* flags)
{
    if (threadIdx.x != 0 || blockIdx.x != 0) return;
    const long long* e64 = (const long long*)ei;
    int ok64 = 1;
    for (int i = 0; i < 128; ++i) {
        long long v = e64[i];
        if (v < 0 || v >= N_NODES) { ok64 = 0; break; }
    }
    const __hip_bfloat16* xb = (const __hip_bfloat16*)x;
    int cnt = 0;
    for (int i = 0; i < 256; ++i) {
        float v = fabsf(__bfloat162float(xb[i]));
        if (v == 0.0f || (v > 9.5367431640625e-7f && v < 1.0e6f)) ++cnt;
    }
    flags[0] = ok64;
    flags[1] = (cnt >= 240) ? 1 : 0;
}

__global__ void zero98(int* __restrict__ pcnt)
{
    int i = threadIdx.x;
    if (i < N_BKT) pcnt[i] = 0;
}

// ---- pass A: bucket histogram, LDS-privatized ----
__global__ __launch_bounds__(1024) void radix_count(const void* ei, int* __restrict__ pcnt,
                                                    const int* __restrict__ flags)
{
    __shared__ int hist[N_BKT];
    const int t = threadIdx.x;
    if (t < N_BKT) hist[t] = 0;
    __syncthreads();
    const int base = blockIdx.x * EPB;
    const int n = min(EPB, N_EDGES - base);
    const int is64 = flags[0];
    for (int j = t; j < n; j += 1024) {
        int d = ldi(ei, (long long)N_EDGES + base + j, is64);
        atomicAdd(&hist[d >> 10], 1);
    }
    __syncthreads();
    if (t < N_BKT) atomicAdd(&pcnt[t], hist[t]);
}

// ---- prefix scan over 98 bucket counts (single block of 128) ----
__global__ void scan98(const int* __restrict__ cnt, int* __restrict__ base,
                       int* __restrict__ cursor)
{
    __shared__ int tmp[128];
    const int t = threadIdx.x;
    int v = (t < N_BKT) ? cnt[t] : 0;
    tmp[t] = v;
    __syncthreads();
    for (int off = 1; off < 128; off <<= 1) {
        int add = (t >= off) ? tmp[t - off] : 0;
        __syncthreads();
        tmp[t] += add;
        __syncthreads();
    }
    if (t < N_BKT) { base[t] = tmp[t] - v; cursor[t] = tmp[t] - v; }
    if (t == 127) base[N_BKT] = tmp[127];   // == N_EDGES
}

// ---- pass B: LDS-staged radix partition into contiguous bucket regions ----
__global__ __launch_bounds__(1024) void radix_scatter(const void* ei, const void* ew,
                                                      int* __restrict__ gcursor,
                                                      uint2* __restrict__ temp,
                                                      const int* __restrict__ flags)
{
    __shared__ uint2 stage[EPB];                  // 64 KB
    __shared__ unsigned char stgb[EPB];           // 8 KB
    __shared__ int hist[128], scan_s[128];
    __shared__ int gbase[N_BKT], lcur[N_BKT];
    const int t = threadIdx.x;
    if (t < 128) hist[t] = 0;
    __syncthreads();

    const int base = blockIdx.x * EPB;
    const int n = min(EPB, N_EDGES - base);
    const int is64 = flags[0], isbf = flags[1];

    int  bkt[8];
    uint2 pk[8];
#pragma unroll
    for (int j = 0; j < 8; ++j) {
        int i = j * 1024 + t;
        bkt[j] = -1;
        if (i < n) {
            int e = base + i;
            int s = ldi(ei, e, is64);
            int d = ldi(ei, (long long)N_EDGES + e, is64);
            float w = ldf(ew, e, isbf);
            bkt[j] = d >> 10;
            pk[j].x = (unsigned)s | ((unsigned)(d & (NPB - 1)) << 17);
            pk[j].y = (unsigned)f2us(w);
            atomicAdd(&hist[bkt[j]], 1);
        }
    }
    __syncthreads();
    // inclusive scan over 128 (only t<128 active; all threads hit barriers)
    if (t < 128) scan_s[t] = hist[t];
    __syncthreads();
    for (int off = 1; off < 128; off <<= 1) {
        int add = 0;
        if (t < 128 && t >= off) add = scan_s[t - off];
        __syncthreads();
        if (t < 128) scan_s[t] += add;
        __syncthreads();
    }
    if (t < N_BKT) {
        int excl = scan_s[t] - hist[t];
        lcur[t] = excl;
        // adjust so that global addr = gbase[b] + stage_index
        gbase[t] = atomicAdd(&gcursor[t], hist[t]) - excl;
    }
    __syncthreads();
#pragma unroll
    for (int j = 0; j < 8; ++j) {
        if (bkt[j] >= 0) {
            int pos = atomicAdd(&lcur[bkt[j]], 1);
            stage[pos] = pk[j];
            stgb[pos] = (unsigned char)bkt[j];
        }
    }
    __syncthreads();
#pragma unroll
    for (int j = 0; j < 8; ++j) {
        int i = j * 1024 + t;
        if (i < n) {
            int b = stgb[i];
            temp[gbase[b] + i] = stage[i];
        }
    }
}

// ---- pass C: per-bucket CSR finalize (1024 nodes); writes deg/row_start/inv_deg ----
// csr entry: src:17b | bf16-weight-without-sign:15b (weights >= 0)
__global__ __launch_bounds__(1024) void csr_build(const uint2* __restrict__ temp,
                          const int* __restrict__ pbase,
                          unsigned int* __restrict__ csr_pk,
                          int* __restrict__ deg, int* __restrict__ row_start,
                          float* __restrict__ inv_deg)
{
    __shared__ int cnt[NPB], scan_s[NPB], cur[NPB];
    const int b = blockIdx.x;
    const int t = threadIdx.x;
    cnt[t] = 0;
    __syncthreads();
    const int bs = pbase[b];
    const int be = pbase[b + 1];
    for (int i = bs + t; i < be; i += NPB)
        atomicAdd(&cnt[(temp[i].x >> 17) & (NPB - 1)], 1);
    __syncthreads();
    int v = cnt[t];
    scan_s[t] = v;
    __syncthreads();
    for (int off = 1; off < NPB; off <<= 1) {
        int add = (t >= off) ? scan_s[t - off] : 0;
        __syncthreads();
        scan_s[t] += add;
        __syncthreads();
    }
    int excl = bs + scan_s[t] - v;
    cur[t] = excl;
    int node = b * NPB + t;
    if (node < N_NODES) {
        deg[node]       = v;
        row_start[node] = excl;
        inv_deg[node]   = 1.0f / (float)max(v, 1);
    }
    __syncthreads();
    for (int i = bs + t; i < be; i += NPB) {
        uint2 e = temp[i];
        int k = (e.x >> 17) & (NPB - 1);
        int pos = atomicAdd(&cur[k], 1);
        csr_pk[pos] = (e.x & 0x1FFFFu) | ((e.y & 0x7FFFu) << 17);
    }
}

// ---- embedding via MFMA: h = relu(x @ W + b), [N,100pad128] @ [128,64] ----
__global__ void embed_mfma(const void* x, const void* W, const void* b,
                           __hip_bfloat16* __restrict__ h, const int* __restrict__ flags)
{
    constexpr int KP = 136;
    __shared__ unsigned short W_s[H_DIM * KP];
    __shared__ float b_s[H_DIM];
    const int t = threadIdx.x;
    const int isbf = flags[1];
    for (int i = t; i < 128 * H_DIM; i += 256) {
        int k = i >> 6, n = i & 63;
        float v = (k < F_IN) ? ldf(W, (long long)k * H_DIM + n, isbf) : 0.0f;
        W_s[n * KP + k] = f2us(v);
    }
    if (t < H_DIM) b_s[t] = ldf(b, t, isbf);
    __syncthreads();

    const int wave = t >> 6, lane = t & 63, c = lane & 15, quad = lane >> 4;
    short8 bfrag[4][4];
#pragma unroll
    for (int nt = 0; nt < 4; ++nt)
#pragma unroll
        for (int kt = 0; kt < 4; ++kt)
            bfrag[nt][kt] = *(const short8*)&W_s[(nt * 16 + c) * KP + kt * 32 + quad * 8];

    const int nb = (blockIdx.x * 4 + wave) * 16;
    if (nb >= N_NODES) return;
    int node = nb + c; if (node >= N_NODES) node = N_NODES - 1;

    short8 afrag[4];
#pragma unroll
    for (int kt = 0; kt < 4; ++kt) {
        short8 a;
#pragma unroll
        for (int j = 0; j < 8; ++j) {
            int k = kt * 32 + quad * 8 + j;
            float v = (k < F_IN) ? ldf(x, (long long)node * F_IN + k, isbf) : 0.0f;
            a[j] = (short)f2us(v);
        }
        afrag[kt] = a;
    }

    f32x4 acc[4] = {};
#pragma unroll
    for (int nt = 0; nt < 4; ++nt)
#pragma unroll
        for (int kt = 0; kt < 4; ++kt)
            acc[nt] = __builtin_amdgcn_mfma_f32_16x16x32_bf16(afrag[kt], bfrag[nt][kt], acc[nt], 0, 0, 0);

#pragma unroll
    for (int nt = 0; nt < 4; ++nt)
#pragma unroll
        for (int reg = 0; reg < 4; ++reg) {
            int nn = nb + quad * 4 + reg;
            int col = nt * 16 + c;
            if (nn < N_NODES) {
                float v = fmaxf(acc[nt][reg] + b_s[col], 0.0f);
                h[(size_t)nn * H_DIM + col] = __float2bfloat16(v);
            }
        }
}

// ---- gather: mean[n] = inv_deg * sum_j w_j * h[src_j], wave per node ----
// lane = (r,c): r = neighbor sub-index (8), c = feature oct (8 x 8 features, 16B loads)
template <bool USE_W>
__global__ void gather_mean(const __hip_bfloat16* __restrict__ h,
                            const unsigned int* __restrict__ csr_pk,
                            const int* __restrict__ row_start,
                            const int* __restrict__ deg,
                            const float* __restrict__ inv_deg,
                            __hip_bfloat16* __restrict__ mean)
{
    const int lane = threadIdx.x & 63;
    const int c = lane & 7;
    const int r = lane >> 3;
    const int wid = blockIdx.x * 4 + (threadIdx.x >> 6);
    const int nw  = gridDim.x * 4;

    for (int n = wid; n < N_NODES; n += nw) {
        const int start = row_start[n];
        const int d     = deg[n];
        unsigned int ev = 0;
        if (lane < d) ev = csr_pk[start + lane];
        const int dmain = min(d, 64);
        float a0 = 0.f, a1 = 0.f, a2 = 0.f, a3 = 0.f;
        float a4 = 0.f, a5 = 0.f, a6 = 0.f, a7 = 0.f;
#pragma unroll 2
        for (int j0 = 0; j0 < dmain; j0 += 8) {
            unsigned int e = __shfl(ev, j0 + r);
            int s = e & 0x1FFFF;                 // invalid lanes: ev=0 -> s=0, w=0
            float w;
            if (USE_W) w = __uint_as_float((e & 0xFFFE0000u) >> 1);
            else       w = (j0 + r < dmain) ? 1.0f : 0.0f;
            uint4 hv = *(const uint4*)(h + (size_t)s * H_DIM + 8 * c);
            a0 = fmaf(w, __uint_as_float(hv.x << 16),          a0);
            a1 = fmaf(w, __uint_as_float(hv.x & 0xFFFF0000u),  a1);
            a2 = fmaf(w, __uint_as_float(hv.y << 16),          a2);
            a3 = fmaf(w, __uint_as_float(hv.y & 0xFFFF0000u),  a3);
            a4 = fmaf(w, __uint_as_float(hv.z << 16),          a4);
            a5 = fmaf(w, __uint_as_float(hv.z & 0xFFFF0000u),  a5);
            a6 = fmaf(w, __uint_as_float(hv.w << 16),          a6);
            a7 = fmaf(w, __uint_as_float(hv.w & 0xFFFF0000u),  a7);
        }
        for (int j = 64 + r; j < d; j += 8) {
            unsigned int e = csr_pk[start + j];
            int s = e & 0x1FFFF;
            float w = USE_W ? __uint_as_float((e & 0xFFFE0000u) >> 1) : 1.0f;
            uint4 hv = *(const uint4*)(h + (size_t)s * H_DIM + 8 * c);
            a0 = fmaf(w, __uint_as_float(hv.x << 16),          a0);
            a1 = fmaf(w, __uint_as_float(hv.x & 0xFFFF0000u),  a1);
            a2 = fmaf(w, __uint_as_float(hv.y << 16),          a2);
            a3 = fmaf(w, __uint_as_float(hv.y & 0xFFFF0000u),  a3);
            a4 = fmaf(w, __uint_as_float(hv.z << 16),          a4);
            a5 = fmaf(w, __uint_as_float(hv.z & 0xFFFF0000u),  a5);
            a6 = fmaf(w, __uint_as_float(hv.w << 16),          a6);
            a7 = fmaf(w, __uint_as_float(hv.w & 0xFFFF0000u),  a7);
        }
#pragma unroll
        for (int m = 8; m <= 32; m <<= 1) {
            a0 += __shfl_xor(a0, m); a1 += __shfl_xor(a1, m);
            a2 += __shfl_xor(a2, m); a3 += __shfl_xor(a3, m);
            a4 += __shfl_xor(a4, m); a5 += __shfl_xor(a5, m);
            a6 += __shfl_xor(a6, m); a7 += __shfl_xor(a7, m);
        }
        if (r == 0) {
            float inv = inv_deg[n];
            uint4 st;
            st.x = (unsigned)f2us(a0 * inv) | ((unsigned)f2us(a1 * inv) << 16);
            st.y = (unsigned)f2us(a2 * inv) | ((unsigned)f2us(a3 * inv) << 16);
            st.z = (unsigned)f2us(a4 * inv) | ((unsigned)f2us(a5 * inv) << 16);
            st.w = (unsigned)f2us(a6 * inv) | ((unsigned)f2us(a7 * inv) << 16);
            *(uint4*)(mean + (size_t)n * H_DIM + 8 * c) = st;
        }
    }
}

// ---- transform via MFMA: out = L2norm([mean|h] @ [Wl;Wr] + b), opt relu ----
template <int COUT, bool RELU, bool FINAL>
__global__ void transform_mfma(const __hip_bfloat16* __restrict__ meanp,
                               const __hip_bfloat16* __restrict__ hp,
                               const void* Wl, const void* bl, const void* Wr,
                               __hip_bfloat16* __restrict__ h_out,
                               const int* __restrict__ flags, void* dout)
{
    constexpr int CP = (COUT + 15) & ~15;
    constexpr int NT = CP / 16;
    constexpr int KP = 136;
    __shared__ unsigned short W_s[CP * KP];
    __shared__ float b_s[CP];
    const int t = threadIdx.x;
    const int isbf = flags[1];
    for (int i = t; i < 128 * CP; i += 256) {
        int k = i / CP, n = i % CP;
        float v = 0.0f;
        if (n < COUT)
            v = (k < 64) ? ldf(Wl, (long long)k * COUT + n, isbf)
                         : ldf(Wr, (long long)(k - 64) * COUT + n, isbf);
        W_s[n * KP + k] = f2us(v);
    }
    if (t < CP) b_s[t] = (t < COUT) ? ldf(bl, t, isbf) : 0.0f;
    __syncthreads();

    const int wave = t >> 6, lane = t & 63, c = lane & 15, quad = lane >> 4;
    short8 bfrag[NT][4];
#pragma unroll
    for (int nt = 0; nt < NT; ++nt)
#pragma unroll
        for (int kt = 0; kt < 4; ++kt)
            bfrag[nt][kt] = *(const short8*)&W_s[(nt * 16 + c) * KP + kt * 32 + quad * 8];

    const int nb = (blockIdx.x * 4 + wave) * 16;
    if (nb >= N_NODES) return;
    int node = nb + c; if (node >= N_NODES) node = N_NODES - 1;

    short8 afrag[4];
#pragma unroll
    for (int kt = 0; kt < 4; ++kt) {
        const __hip_bfloat16* sp = (kt < 2) ? meanp : hp;
        afrag[kt] = *(const short8*)(sp + (size_t)node * H_DIM + (kt & 1) * 32 + quad * 8);
    }

    f32x4 acc[NT] = {};
#pragma unroll
    for (int nt = 0; nt < NT; ++nt)
#pragma unroll
        for (int kt = 0; kt < 4; ++kt)
            acc[nt] = __builtin_amdgcn_mfma_f32_16x16x32_bf16(afrag[kt], bfrag[nt][kt], acc[nt], 0, 0, 0);

    float rs[4];
#pragma unroll
    for (int reg = 0; reg < 4; ++reg) {
        float s2 = 0.f;
#pragma unroll
        for (int nt = 0; nt < NT; ++nt) {
            float v = acc[nt][reg] + b_s[nt * 16 + c];
            acc[nt][reg] = v;
            s2 += v * v;
        }
        s2 += __shfl_xor(s2, 1); s2 += __shfl_xor(s2, 2);
        s2 += __shfl_xor(s2, 4); s2 += __shfl_xor(s2, 8);
        rs[reg] = 1.0f / fmaxf(sqrtf(s2), 1e-12f);
    }

#pragma unroll
    for (int nt = 0; nt < NT; ++nt)
#pragma unroll
        for (int reg = 0; reg < 4; ++reg) {
            int nn  = nb + quad * 4 + reg;
            int col = nt * 16 + c;
            if (nn < N_NODES && col < COUT) {
                float v = acc[nt][reg] * rs[reg];
                if (RELU) v = fmaxf(v, 0.0f);
                if (FINAL) {
                    if (isbf) ((__hip_bfloat16*)dout)[(size_t)nn * COUT + col] = __float2bfloat16(v);
                    else      ((float*)dout)[(size_t)nn * COUT + col] = v;
                } else {
                    h_out[(size_t)nn * H_DIM + col] = __float2bfloat16(v);
                }
            }
        }
}

extern "C" void kernel_launch(void* const* d_in, const int* in_sizes, int n_in,
                              void* d_out, int out_size, void* d_ws, size_t ws_size,
                              hipStream_t stream)
{
    const void* x    = d_in[0];
    const void* ei   = d_in[1];
    const void* ew   = d_in[2];
    const void* embW = d_in[3];
    const void* embB = d_in[4];
    const void* Wl1 = d_in[5];  const void* bl1 = d_in[6];  const void* Wr1 = d_in[7];
    const void* Wl2 = d_in[8];  const void* bl2 = d_in[9];  const void* Wr2 = d_in[10];
    const void* Wl3 = d_in[11]; const void* bl3 = d_in[12]; const void* Wr3 = d_in[13];
    const void* Wl4 = d_in[14]; const void* bl4 = d_in[15]; const void* Wr4 = d_in[16];
    (void)in_sizes; (void)n_in; (void)out_size; (void)ws_size;

    char* ws = (char*)d_ws;
    size_t off = 0;
    auto alloc = [&](size_t bytes) -> void* {
        void* p = ws + off;
        off += (bytes + 255) & ~(size_t)255;
        return p;
    };
    // temp (edge staging, 25.6 MB) is dead after csr_build; hA/hB alias it.
    uint2* temp = (uint2*)alloc((size_t)N_EDGES * sizeof(uint2));
    __hip_bfloat16* hA = (__hip_bfloat16*)temp;
    __hip_bfloat16* hB = (__hip_bfloat16*)((char*)temp + (size_t)N_NODES * H_DIM * 2);
    unsigned int* csr_pk = (unsigned int*)alloc((size_t)N_EDGES * sizeof(unsigned int));
    int*   pcnt    = (int*)  alloc((N_BKT)     * sizeof(int));
    int*   pbase   = (int*)  alloc((N_BKT + 1) * sizeof(int));
    int*   pcursor = (int*)  alloc((N_BKT)     * sizeof(int));
    int*   deg     = (int*)  alloc((size_t)N_NODES * sizeof(int));
    int*   row_st  = (int*)  alloc((size_t)N_NODES * sizeof(int));
    float* inv_deg = (float*)alloc((size_t)N_NODES * sizeof(float));
    int*   flags   = (int*)  alloc(256);

    const int NBr = (N_EDGES + EPB - 1) / EPB;   // 391 radix blocks
    const int NBt = (N_NODES + 63) / 64;         // 1563

    detect_kernel<<<1, 64, 0, stream>>>(ei, x, flags);
    zero98<<<1, 128, 0, stream>>>(pcnt);
    radix_count<<<NBr, 1024, 0, stream>>>(ei, pcnt, flags);
    scan98<<<1, 128, 0, stream>>>(pcnt, pbase, pcursor);
    radix_scatter<<<NBr, 1024, 0, stream>>>(ei, ew, pcursor, temp, flags);
    csr_build<<<N_BKT, NPB, 0, stream>>>(temp, pbase, csr_pk, deg, row_st, inv_deg);

    embed_mfma<<<NBt, 256, 0, stream>>>(x, embW, embB, hA, flags);

    // layer 1: h=A -> mean in B, out overwrites B
    gather_mean<true><<<2048, 256, 0, stream>>>(hA, csr_pk, row_st, deg, inv_deg, hB);
    transform_mfma<H_DIM, true, false><<<NBt, 256, 0, stream>>>(
        hB, hA, Wl1, bl1, Wr1, hB, flags, d_out);
    // layer 2: h=B -> mean in A, out overwrites A
    gather_mean<true><<<2048, 256, 0, stream>>>(hB, csr_pk, row_st, deg, inv_deg, hA);
    transform_mfma<H_DIM, true, false><<<NBt, 256, 0, stream>>>(
        hA, hB, Wl2, bl2, Wr2, hA, flags, d_out);
    // layer 3: h=A -> mean in B, out overwrites B
    gather_mean<true><<<2048, 256, 0, stream>>>(hA, csr_pk, row_st, deg, inv_deg, hB);
    transform_mfma<H_DIM, true, false><<<NBt, 256, 0, stream>>>(
        hB, hA, Wl3, bl3, Wr3, hB, flags, d_out);
    // layer 4: h=B -> mean in A (unweighted), out -> d_out
    gather_mean<false><<<2048, 256, 0, stream>>>(hB, csr_pk, row_st, deg, inv_deg, hA);
    transform_mfma<C_NUM, false, true><<<NBt, 256, 0, stream>>>(
        hA, hB, Wl4, bl4, Wr4, nullptr, flags, d_out);
}